// Round 1
// baseline (480.249 us; speedup 1.0000x reference)
//
#include <hip/hip_runtime.h>
#include <cstdint>
#include <cstddef>

#define T_STEPS 1024
#define SEG     8
#define NSEG    (T_STEPS / SEG)   // 128 segments
#define NBLK    256               // 512 batch / 2 per block
#define LOG2E   1.4426950408889634f
// weight-row permutation: tile (k, col) -> within-gate unit u.
// Makes each act lane's two h values contiguous (one 2-byte ring write).
#define UPERM(k, c) ((((c) << 1) + ((k) & 1)) + (((k) >> 1) << 5))

typedef __attribute__((ext_vector_type(8))) _Float16 half8;
typedef __attribute__((ext_vector_type(4))) float    f32x4;
typedef __attribute__((ext_vector_type(4))) int      i32x4;

static __device__ __forceinline__ float fexp2(float x) {
#if defined(__has_builtin) && __has_builtin(__builtin_amdgcn_exp2f)
  return __builtin_amdgcn_exp2f(x);
#else
  return __exp2f(x);
#endif
}
// pre-acts arrive PRE-SCALED by log2e
static __device__ __forceinline__ float sigm2(float a) {
  return __builtin_amdgcn_rcpf(1.0f + fexp2(-a));
}
static __device__ __forceinline__ float tanhg2(float a) {
  return 2.0f * __builtin_amdgcn_rcpf(1.0f + fexp2(-(a + a))) - 1.0f;
}
static __device__ __forceinline__ float tanhc(float c) {   // tanh(c), c unscaled
  return 1.0f - 2.0f * __builtin_amdgcn_rcpf(1.0f + fexp2(c * (2.0f * LOG2E)));
}

static __device__ __forceinline__ half8 load8s(const float* s, float sc) {
  float4 a = ((const float4*)s)[0];
  float4 b = ((const float4*)s)[1];
  half8 h;
  h[0] = (_Float16)(a.x * sc); h[1] = (_Float16)(a.y * sc);
  h[2] = (_Float16)(a.z * sc); h[3] = (_Float16)(a.w * sc);
  h[4] = (_Float16)(b.x * sc); h[5] = (_Float16)(b.y * sc);
  h[6] = (_Float16)(b.z * sc); h[7] = (_Float16)(b.w * sc);
  return h;
}
// quantize 16 contiguous floats with scale s -> 16 i8 packed in 4 dwords
static __device__ __forceinline__ i32x4 quant16(const float* src, float s) {
  union { i32x4 v; signed char b[16]; } u;
  #pragma unroll
  for (int j = 0; j < 16; ++j) u.b[j] = (signed char)__float2int_rn(src[j] * s);
  return u.v;
}

// lgkm-only workgroup barrier (R8-verified): global loads float across it.
static __device__ __forceinline__ void barrier_lds() {
  __asm__ volatile("s_waitcnt lgkmcnt(0)\n\ts_barrier" ::: "memory");
}

// R17: wave-specialized producer/consumer. The per-timestep workgroup barrier
// (1026 of them) + cross-wave h roundtrip was the critical path (step ~900cy vs
// ~350cy dependence floor). Now each recurrence is ONE wave (16 i8 MFMAs cover
// all 256 gate rows, K=64 per instr); h write->read is intra-wave (lgkm-ordered,
// no s_barrier). Off-chain matmuls run a segment (8 steps) ahead in other waves:
//   w0: L1 recurrence (h1 -> 32-slot ring)        [seg s]
//   w1: L2 recurrence (only W_hh2 kstep on chain) [seg s-2]
//   w2: xg2 = log2e*(W_ih2 @ h1 + b) from ring    [seg s-1]
//   w3: xg1 = log2e*(W_ih1 @ x_t + b) from global [seg s+1]
// Barriers: 1 per segment (130 total). Quant scheme unchanged (per-row i8
// weights, h i8 scale 127, log2e folded); L2 now has separate row scales for
// W_ih2 / W_hh2 (was shared) -> absmax equal or better.
__global__ __launch_bounds__(256, 1) void lstm_fused(
    const float* __restrict__ x,
    const float* __restrict__ w_ih1, const float* __restrict__ w_hh1,
    const float* __restrict__ b_ih1, const float* __restrict__ b_hh1,
    const float* __restrict__ w_ih2, const float* __restrict__ w_hh2,
    const float* __restrict__ b_ih2, const float* __restrict__ b_hh2,
    const float* __restrict__ fc1_w, const float* __restrict__ fc1_b,
    const float* __restrict__ fc2_w, const float* __restrict__ fc2_b,
    const float* __restrict__ ln_g, const float* __restrict__ ln_b,
    float* __restrict__ out)
{
  __shared__ __align__(16) signed char h1ring[32][2][64];   // 4 KB, 4-seg history
  __shared__ __align__(16) signed char h2ring[2][2][64];    // 256 B, w1-private
  __shared__ __align__(16) float xg1b[2][SEG][2][64][4];    // 32 KB (dbuf)
  __shared__ __align__(16) float xg2b[2][SEG][2][64][4];    // 32 KB (dbuf)
  __shared__ __align__(16) float hfin[2][64];
  __shared__ __align__(16) float y1s[2][128];
  __shared__ __align__(16) float y2s[2][128];
  __shared__ float redmu[2], redrs[2];

  const int t   = threadIdx.x;
  const int blk = blockIdx.x;
  const int l   = t & 63;
  const int w   = t >> 6;       // wave role 0..3
  const int col = l & 15;
  const int q   = l >> 4;       // quad (K-slice for fragments)

  // ---- zero h rings (h_{-1} = 0) ----
  {
    int* hp = (int*)h1ring;
    #pragma unroll
    for (int i = 0; i < 4; ++i) hp[t + i * 256] = 0;
    if (t < 64) ((int*)h2ring)[t] = 0;
  }

  const i32x4 zi = (i32x4){0, 0, 0, 0};
  f32x4 zf; zf[0] = 0.f; zf[1] = 0.f; zf[2] = 0.f; zf[3] = 0.f;

  // ---- stationary per-role weights ----
  i32x4 wq[4][4];      // w0: w_hh1 | w1: w_hh2 | w2: w_ih2  (per-row i8)
  half8 wbx[4][4];     // w3: w_ih1 f16, log2e-folded
  f32x4 fsa0, fsa1;    // w0/w1: act dequant scales for this lane's 2 units
  float fsx[4][4];     // w2: dequant scales
  float bL[4][4];      // w2/w3: log2e-scaled biases

  if (w < 3) {
    const float* W = (w == 0) ? w_hh1 : (w == 1) ? w_hh2 : w_ih2;
    float fs[4][4];
    #pragma unroll
    for (int g = 0; g < 4; ++g) {
      #pragma unroll
      for (int k = 0; k < 4; ++k) {
        const int r = g * 64 + UPERM(k, col);
        const float* p = W + r * 64 + q * 16;
        float m = 0.0f;
        #pragma unroll
        for (int j = 0; j < 16; ++j) m = fmaxf(m, fabsf(p[j]));
        m = fmaxf(m, __shfl_xor(m, 16, 64));
        m = fmaxf(m, __shfl_xor(m, 32, 64));
        wq[g][k] = quant16(p, 127.0f / m);
        fs[g][k] = m * (LOG2E / 16129.0f);
      }
    }
    if (w == 2) {
      #pragma unroll
      for (int g = 0; g < 4; ++g) {
        #pragma unroll
        for (int k = 0; k < 4; ++k) {
          const int r = g * 64 + UPERM(k, col);
          fsx[g][k] = fs[g][k];
          bL[g][k]  = (b_ih2[r] + b_hh2[r]) * LOG2E;
        }
      }
    } else if (l & 32) {   // act lanes 32-63 own tiles k=2,3
      fsa0[0] = fs[0][2]; fsa0[1] = fs[1][2]; fsa0[2] = fs[2][2]; fsa0[3] = fs[3][2];
      fsa1[0] = fs[0][3]; fsa1[1] = fs[1][3]; fsa1[2] = fs[2][3]; fsa1[3] = fs[3][3];
    } else {               // lanes 0-31 own tiles k=0,1
      fsa0[0] = fs[0][0]; fsa0[1] = fs[1][0]; fsa0[2] = fs[2][0]; fsa0[3] = fs[3][0];
      fsa1[0] = fs[0][1]; fsa1[1] = fs[1][1]; fsa1[2] = fs[2][1]; fsa1[3] = fs[3][1];
    }
  } else {
    #pragma unroll
    for (int g = 0; g < 4; ++g) {
      #pragma unroll
      for (int k = 0; k < 4; ++k) {
        const int r = g * 64 + UPERM(k, col);
        wbx[g][k] = load8s(w_ih1 + r * 32 + q * 8, LOG2E);
        bL[g][k]  = (b_ih1[r] + b_hh1[r]) * LOG2E;
      }
    }
  }

  // recurrence-lane constants (C rows = A rows, batch pattern (0000 1111)x2)
  const int ab    = q & 1;                              // act batch
  const int u0    = ((l & 15) << 1) + ((l >> 5) << 5);  // first owned unit
  const int bfrag = ((l & 15) >> 2) & 1;                // A-frag row -> batch
  const int hi    = l & 32;
  // producer A-row mapping: row = l&15 -> (t_local, batch)
  const int arow  = (l & 15) >> 1;
  const int axb   = l & 1;

  float c0 = 0.0f, c1 = 0.0f;

  // ---- w3: xg1[tau] = log2e*(W_ih1 @ x + b1) for 8 steps, one f16 A-frag ----
  auto produce_xg1 = [&](int tau) {
    const float* xs = x + ((size_t)(2 * blk + axb) * T_STEPS + (tau * SEG + arow)) * 32 + q * 8;
    const float4 va = ((const float4*)xs)[0];
    const float4 vb = ((const float4*)xs)[1];
    half8 xf;
    xf[0] = (_Float16)va.x; xf[1] = (_Float16)va.y;
    xf[2] = (_Float16)va.z; xf[3] = (_Float16)va.w;
    xf[4] = (_Float16)vb.x; xf[5] = (_Float16)vb.y;
    xf[6] = (_Float16)vb.z; xf[7] = (_Float16)vb.w;
    f32x4 accf[4][4];
    #pragma unroll
    for (int g = 0; g < 4; ++g)
      #pragma unroll
      for (int k = 0; k < 4; ++k)
        accf[g][k] = __builtin_amdgcn_mfma_f32_16x16x32_f16(xf, wbx[g][k], zf, 0, 0, 0);
    float* dst = &xg1b[tau & 1][0][0][0][0];
    #pragma unroll
    for (int k = 0; k < 4; ++k) {
      #pragma unroll
      for (int r = 0; r < 4; ++r) {
        const int row = q * 4 + r;          // row = t_local*2 + batch
        f32x4 v;
        v[0] = accf[0][k][r] + bL[0][k];
        v[1] = accf[1][k][r] + bL[1][k];
        v[2] = accf[2][k][r] + bL[2][k];
        v[3] = accf[3][k][r] + bL[3][k];
        *(f32x4*)(dst + (size_t)(row * 64 + UPERM(k, col)) * 4) = v;
      }
    }
  };

  // ---- w2: xg2[sg] = log2e*(W_ih2 @ h1 + b2) from h1 ring, one i8 A-frag ----
  auto produce_xg2 = [&](int sg) {
    const i32x4 a = *(const i32x4*)((const signed char*)h1ring +
                    (size_t)((((sg * SEG + arow) & 31) * 128) + axb * 64 + q * 16));
    i32x4 acc[4][4];
    #pragma unroll
    for (int g = 0; g < 4; ++g)
      #pragma unroll
      for (int k = 0; k < 4; ++k)
        acc[g][k] = __builtin_amdgcn_mfma_i32_16x16x64_i8(a, wq[g][k], zi, 0, 0, 0);
    float* dst = &xg2b[sg & 1][0][0][0][0];
    #pragma unroll
    for (int k = 0; k < 4; ++k) {
      #pragma unroll
      for (int r = 0; r < 4; ++r) {
        const int row = q * 4 + r;
        f32x4 v;
        v[0] = bL[0][k] + fsx[0][k] * (float)acc[0][k][r];
        v[1] = bL[1][k] + fsx[1][k] * (float)acc[1][k][r];
        v[2] = bL[2][k] + fsx[2][k] * (float)acc[2][k][r];
        v[3] = bL[3][k] + fsx[3][k] * (float)acc[3][k][r];
        *(f32x4*)(dst + (size_t)(row * 64 + UPERM(k, col)) * 4) = v;
      }
    }
  };

  // ---- recurrence: 8 steps, barrier-free (intra-wave lgkm ordering only) ----
  auto run_seg = [&](const float* XG, signed char* RING, int RM, int t0, int isl2) {
    #pragma unroll
    for (int j8 = 0; j8 < SEG; ++j8) {
      const int tt = t0 + j8;
      // previous step's h frag (own write, lgkm-ordered; char stores alias-safe)
      const i32x4 a = *(const i32x4*)(RING + ((tt - 1) & RM) * 128 + bfrag * 64 + q * 16);
      // per-step gate pre-acts from producer (issued early; latency hidden)
      const f32x4 xv0 = *(const f32x4*)(XG + (size_t)((j8 * 2 + ab) * 64 + u0) * 4);
      const f32x4 xv1 = *(const f32x4*)(XG + (size_t)((j8 * 2 + ab) * 64 + u0 + 1) * 4);
      i32x4 acc[4][4];
      #pragma unroll
      for (int g = 0; g < 4; ++g)
        #pragma unroll
        for (int k = 0; k < 4; ++k)
          acc[g][k] = __builtin_amdgcn_mfma_i32_16x16x64_i8(a, wq[g][k], zi, 0, 0, 0);
      // unit 0 (tile k = hi?2:0)
      const int i00 = hi ? acc[0][2][0] : acc[0][0][0];
      const int i01 = hi ? acc[1][2][0] : acc[1][0][0];
      const int i02 = hi ? acc[2][2][0] : acc[2][0][0];
      const int i03 = hi ? acc[3][2][0] : acc[3][0][0];
      const float p00 = xv0[0] + fsa0[0] * (float)i00;
      const float p01 = xv0[1] + fsa0[1] * (float)i01;
      const float p02 = xv0[2] + fsa0[2] * (float)i02;
      const float p03 = xv0[3] + fsa0[3] * (float)i03;
      const float gi0 = sigm2(p00), gf0 = sigm2(p01);
      const float gg0 = tanhg2(p02), go0 = sigm2(p03);
      c0 = gf0 * c0 + gi0 * gg0;
      const float h0 = go0 * tanhc(c0);
      // unit 1 (tile k = hi?3:1)
      const int i10 = hi ? acc[0][3][0] : acc[0][1][0];
      const int i11 = hi ? acc[1][3][0] : acc[1][1][0];
      const int i12 = hi ? acc[2][3][0] : acc[2][1][0];
      const int i13 = hi ? acc[3][3][0] : acc[3][1][0];
      const float p10 = xv1[0] + fsa1[0] * (float)i10;
      const float p11 = xv1[1] + fsa1[1] * (float)i11;
      const float p12 = xv1[2] + fsa1[2] * (float)i12;
      const float p13 = xv1[3] + fsa1[3] * (float)i13;
      const float gi1 = sigm2(p10), gf1 = sigm2(p11);
      const float gg1 = tanhg2(p12), go1 = sigm2(p13);
      c1 = gf1 * c1 + gi1 * gg1;
      const float h1v = go1 * tanhc(c1);
      // quantize + ring write (char stores: may-alias, keeps RAW ordering)
      signed char* wp = RING + (tt & RM) * 128 + ab * 64 + u0;
      wp[0] = (signed char)__float2int_rn(h0  * 127.0f);
      wp[1] = (signed char)__float2int_rn(h1v * 127.0f);
      if (isl2 && tt == T_STEPS - 1) {
        hfin[ab][u0]     = h0;
        hfin[ab][u0 + 1] = h1v;
      }
    }
  };

  // ---- prime xg1 for segment 0 (zero-writes also drain at this barrier) ----
  if (w == 3) produce_xg1(0);
  barrier_lds();

  // ---- segmented pipeline: w0 @ s, w2 @ s-1, w1 @ s-2, w3 @ s+1 ----
  for (int s = 0; s <= NSEG + 1; ++s) {
    if (w == 0) {
      if (s < NSEG)
        run_seg(&xg1b[s & 1][0][0][0][0], (signed char*)h1ring, 31, s * SEG, 0);
    } else if (w == 1) {
      const int sg = s - 2;
      if (sg >= 0)
        run_seg(&xg2b[sg & 1][0][0][0][0], (signed char*)h2ring, 1, sg * SEG, 1);
    } else if (w == 2) {
      const int sg = s - 1;
      if (sg >= 0 && sg < NSEG) produce_xg2(sg);
    } else {
      if (s + 1 < NSEG) produce_xg1(s + 1);
    }
    barrier_lds();
  }

  __syncthreads();   // full drain before epilogue

  // ---- head: y = LN(relu(hT@fc1^T+b1)@fc2^T+b2), 2 batch rows ----
  if (t < 256) {
    const int bi = t >> 7, j = t & 127;
    float accv = fc1_b[j];
    const float4* w4 = (const float4*)(fc1_w + j * 64);
    const float4* h4 = (const float4*)hfin[bi];
    #pragma unroll
    for (int qq = 0; qq < 16; ++qq) {
      float4 wv = w4[qq]; float4 hv = h4[qq];
      accv += wv.x * hv.x + wv.y * hv.y + wv.z * hv.z + wv.w * hv.w;
    }
    y1s[bi][j] = fmaxf(accv, 0.0f);
  }
  __syncthreads();
  if (t < 256) {
    const int bi = t >> 7, j = t & 127;
    float accv = fc2_b[j];
    const float4* w4 = (const float4*)(fc2_w + j * 128);
    const float4* y4 = (const float4*)y1s[bi];
    #pragma unroll
    for (int qq = 0; qq < 32; ++qq) {
      float4 wv = w4[qq]; float4 yv = y4[qq];
      accv += wv.x * yv.x + wv.y * yv.y + wv.z * yv.z + wv.w * yv.w;
    }
    y2s[bi][j] = accv;
  }
  __syncthreads();
  if (t < 128) {
    const int bi = t >> 6, jj = t & 63;
    float s  = y2s[bi][jj] + y2s[bi][64 + jj];
    float qs = y2s[bi][jj] * y2s[bi][jj] + y2s[bi][64 + jj] * y2s[bi][64 + jj];
    #pragma unroll
    for (int off = 32; off > 0; off >>= 1) {
      s  += __shfl_down(s, off, 64);
      qs += __shfl_down(qs, off, 64);
    }
    if (jj == 0) {
      const float mu  = s * (1.0f / 128.0f);
      const float var = qs * (1.0f / 128.0f) - mu * mu;
      redmu[bi] = mu;
      redrs[bi] = rsqrtf(var + 1e-5f);
    }
  }
  __syncthreads();
  if (t < 256) {
    const int bi = t >> 7, j = t & 127;
    out[(size_t)(2 * blk + bi) * 128 + j] =
        (y2s[bi][j] - redmu[bi]) * redrs[bi] * ln_g[j] + ln_b[j];
  }
}

extern "C" void kernel_launch(void* const* d_in, const int* in_sizes, int n_in,
                              void* d_out, int out_size, void* d_ws, size_t ws_size,
                              hipStream_t stream) {
  const float* x     = (const float*)d_in[0];
  const float* w_ih1 = (const float*)d_in[1];
  const float* w_hh1 = (const float*)d_in[2];
  const float* b_ih1 = (const float*)d_in[3];
  const float* b_hh1 = (const float*)d_in[4];
  const float* w_ih2 = (const float*)d_in[5];
  const float* w_hh2 = (const float*)d_in[6];
  const float* b_ih2 = (const float*)d_in[7];
  const float* b_hh2 = (const float*)d_in[8];
  const float* fc1_w = (const float*)d_in[9];
  const float* fc1_b = (const float*)d_in[10];
  const float* fc2_w = (const float*)d_in[11];
  const float* fc2_b = (const float*)d_in[12];
  const float* ln_g  = (const float*)d_in[13];
  const float* ln_b  = (const float*)d_in[14];
  float* out = (float*)d_out;

  lstm_fused<<<NBLK, 256, 0, stream>>>(x, w_ih1, w_hh1, b_ih1, b_hh1,
                                       w_ih2, w_hh2, b_ih2, b_hh2,
                                       fc1_w, fc1_b, fc2_w, fc2_b,
                                       ln_g, ln_b, out);
}

// Round 2
// 409.694 us; speedup vs baseline: 1.1722x; 1.1722x over previous
//
#include <hip/hip_runtime.h>
#include <cstdint>
#include <cstddef>

#define T_STEPS 1024
#define SEG     8
#define NSEG    (T_STEPS / SEG)   // 128 segments
#define NBLK    256               // 512 batch / 2 per block
#define LOG2E   1.4426950408889634f

typedef __attribute__((ext_vector_type(8))) _Float16 half8;
typedef __attribute__((ext_vector_type(4))) float    f32x4;
typedef __attribute__((ext_vector_type(4))) int      i32x4;

static __device__ __forceinline__ float fexp2(float x) {
#if defined(__has_builtin) && __has_builtin(__builtin_amdgcn_exp2f)
  return __builtin_amdgcn_exp2f(x);
#else
  return __exp2f(x);
#endif
}
// pre-acts arrive PRE-SCALED by log2e
static __device__ __forceinline__ float sigm2(float a) {
  return __builtin_amdgcn_rcpf(1.0f + fexp2(-a));
}
static __device__ __forceinline__ float tanhg2(float a) {
  return 2.0f * __builtin_amdgcn_rcpf(1.0f + fexp2(-(a + a))) - 1.0f;
}
static __device__ __forceinline__ float tanhc(float c) {   // tanh(c), c unscaled
  return 1.0f - 2.0f * __builtin_amdgcn_rcpf(1.0f + fexp2(c * (2.0f * LOG2E)));
}

static __device__ __forceinline__ half8 load8s(const float* s, float sc) {
  float4 a = ((const float4*)s)[0];
  float4 b = ((const float4*)s)[1];
  half8 h;
  h[0] = (_Float16)(a.x * sc); h[1] = (_Float16)(a.y * sc);
  h[2] = (_Float16)(a.z * sc); h[3] = (_Float16)(a.w * sc);
  h[4] = (_Float16)(b.x * sc); h[5] = (_Float16)(b.y * sc);
  h[6] = (_Float16)(b.z * sc); h[7] = (_Float16)(b.w * sc);
  return h;
}
// quantize 16 contiguous floats with scale s -> 16 i8 packed in 4 dwords
static __device__ __forceinline__ i32x4 quant16(const float* src, float s) {
  union { i32x4 v; signed char b[16]; } u;
  #pragma unroll
  for (int j = 0; j < 16; ++j) u.b[j] = (signed char)__float2int_rn(src[j] * s);
  return u.v;
}

// lgkm-only workgroup barrier (R8-verified): global loads float across it.
static __device__ __forceinline__ void barrier_lds() {
  __asm__ volatile("s_waitcnt lgkmcnt(0)\n\ts_barrier" ::: "memory");
}

// R18: batch-split recurrences. R17 post-mortem: per-step serial cost ~925cy in
// BOTH R16 (barrier/step) and R17 (barrier-free) -> the chain itself binds:
// per-lane act issue (2 units = 20 trans @8cy + ~70 VALU @2cy ~= 300cy) + LDS
// RAW + 16 MFMA on ONE SIMD. Fix: the 2 batches are independent recurrences ->
// one wave per (layer,batch): 4 chains on 4 SIMDs. h replicated across MFMA
// M-dim (q-group reads same 16B -> LDS broadcast), so each lane activates ONE
// unit (u = lane): act issue halves, ring I/O fully linear. Producers split
// into 4 light waves (one per SIMD) that fill the recurrence stall slots:
//   w0/w1: L1 recurrence b0/b1 [seg s]      w2/w3: L2 recurrence b0/b1 [s-2]
//   w4/w5: xg2 = b2 + fs*(W_ih2 @ h1) halves [s-1]
//   w6/w7: xg1 = log2e*(W_ih1 @ x) + b1 halves [s+1]
// xg layout [step][batch][unit][4gates] -> 16B/lane contiguous reads/writes
// (conflict-free; kills R17's 4-way UPERM conflicts, 1.27e7 -> ~1e6).
// s_setprio(1) around recurrence chains (T5: role diversity per SIMD).
// Quant scheme unchanged (per-row i8 weights, h i8 scale 127, log2e folded).
__global__ __launch_bounds__(512, 2) void lstm_fused(
    const float* __restrict__ x,
    const float* __restrict__ w_ih1, const float* __restrict__ w_hh1,
    const float* __restrict__ b_ih1, const float* __restrict__ b_hh1,
    const float* __restrict__ w_ih2, const float* __restrict__ w_hh2,
    const float* __restrict__ b_ih2, const float* __restrict__ b_hh2,
    const float* __restrict__ fc1_w, const float* __restrict__ fc1_b,
    const float* __restrict__ fc2_w, const float* __restrict__ fc2_b,
    const float* __restrict__ ln_g, const float* __restrict__ ln_b,
    float* __restrict__ out)
{
  __shared__ __align__(16) signed char h1ring[32][2][64];   // 4 KB
  __shared__ __align__(16) signed char h2ring[2][2][64];    // 256 B
  __shared__ __align__(16) float xg1b[2][SEG][2][64][4];    // 32 KB (dbuf)
  __shared__ __align__(16) float xg2b[2][SEG][2][64][4];    // 32 KB (dbuf)
  __shared__ __align__(16) float hfin[2][64];
  __shared__ __align__(16) float y1s[2][128];
  __shared__ __align__(16) float y2s[2][128];
  __shared__ float redmu[2], redrs[2];

  const int t   = threadIdx.x;
  const int blk = blockIdx.x;
  const int l   = t & 63;
  const int w   = t >> 6;       // wave role 0..7
  const int col = l & 15;
  const int q   = l >> 4;       // quad (K-slice)
  const int myb = w & 1;        // recurrence waves: batch; producers: k-half
  const int kbase = (w & 1) * 2;

  // ---- zero h rings (h_{-1} = 0) ----
  ((int*)h1ring)[t]       = 0;
  ((int*)h1ring)[t + 512] = 0;
  if (t < 64) ((int*)h2ring)[t] = 0;

  const i32x4 zi = (i32x4){0, 0, 0, 0};
  f32x4 zf; zf[0] = 0.f; zf[1] = 0.f; zf[2] = 0.f; zf[3] = 0.f;

  // ---- stationary per-role weights ----
  i32x4 wq[4][4];      // w0-3: recurrence W_hh (full)
  i32x4 wq2[4][2];     // w4/w5: W_ih2 half
  half8 wbx[4][2];     // w6/w7: W_ih1 half (f16, log2e-folded)
  f32x4 fsa;           // w0-3: this lane's unit row scales (4 gates)
  float fsx[4][2];     // w4/w5: dequant scales
  float bL[4][2];      // w4-7: log2e-scaled biases

  if (w < 4) {
    const float* W = (w < 2) ? w_hh1 : w_hh2;
    float fsq[4][4];
    #pragma unroll
    for (int g = 0; g < 4; ++g) {
      #pragma unroll
      for (int k = 0; k < 4; ++k) {
        const int r = g * 64 + k * 16 + col;       // unit u = k*16+col, gate g
        const float* p = W + r * 64 + q * 16;
        float m = 0.0f;
        #pragma unroll
        for (int j = 0; j < 16; ++j) m = fmaxf(m, fabsf(p[j]));
        m = fmaxf(m, __shfl_xor(m, 16, 64));
        m = fmaxf(m, __shfl_xor(m, 32, 64));
        wq[g][k] = quant16(p, 127.0f / m);
        fsq[g][k] = m * (LOG2E / 16129.0f);
      }
    }
    // lane's unit is u = l = q*16+col -> needs fsq[g][q] (static-index select)
    #pragma unroll
    for (int g = 0; g < 4; ++g) {
      const float v01 = (q & 1) ? fsq[g][1] : fsq[g][0];
      const float v23 = (q & 1) ? fsq[g][3] : fsq[g][2];
      fsa[g] = (q & 2) ? v23 : v01;
    }
  } else if (w < 6) {
    #pragma unroll
    for (int g = 0; g < 4; ++g) {
      #pragma unroll
      for (int k2 = 0; k2 < 2; ++k2) {
        const int r = g * 64 + (kbase + k2) * 16 + col;
        const float* p = w_ih2 + r * 64 + q * 16;
        float m = 0.0f;
        #pragma unroll
        for (int j = 0; j < 16; ++j) m = fmaxf(m, fabsf(p[j]));
        m = fmaxf(m, __shfl_xor(m, 16, 64));
        m = fmaxf(m, __shfl_xor(m, 32, 64));
        wq2[g][k2] = quant16(p, 127.0f / m);
        fsx[g][k2] = m * (LOG2E / 16129.0f);
        bL[g][k2]  = (b_ih2[r] + b_hh2[r]) * LOG2E;
      }
    }
  } else {
    #pragma unroll
    for (int g = 0; g < 4; ++g) {
      #pragma unroll
      for (int k2 = 0; k2 < 2; ++k2) {
        const int r = g * 64 + (kbase + k2) * 16 + col;
        wbx[g][k2] = load8s(w_ih1 + r * 32 + q * 8, LOG2E);
        bL[g][k2]  = (b_ih1[r] + b_hh1[r]) * LOG2E;
      }
    }
  }

  // producer A-row mapping: row = l&15 = 2*t_local + batch
  const int tl  = (l & 15) >> 1;
  const int axb = l & 1;

  float c = 0.0f;

  // ---- w6/w7: xg1[tau] = log2e*(W_ih1 @ x) + b1 (this wave's k-half) ----
  auto produce_xg1 = [&](int tau) {
    const float* xs = x + ((size_t)(2 * blk + axb) * T_STEPS + (tau * SEG + tl)) * 32 + q * 8;
    const float4 va = ((const float4*)xs)[0];
    const float4 vb = ((const float4*)xs)[1];
    half8 xf;
    xf[0] = (_Float16)va.x; xf[1] = (_Float16)va.y;
    xf[2] = (_Float16)va.z; xf[3] = (_Float16)va.w;
    xf[4] = (_Float16)vb.x; xf[5] = (_Float16)vb.y;
    xf[6] = (_Float16)vb.z; xf[7] = (_Float16)vb.w;
    f32x4 accf[4][2];
    #pragma unroll
    for (int g = 0; g < 4; ++g)
      #pragma unroll
      for (int k2 = 0; k2 < 2; ++k2)
        accf[g][k2] = __builtin_amdgcn_mfma_f32_16x16x32_f16(xf, wbx[g][k2], zf, 0, 0, 0);
    float* dst = &xg1b[tau & 1][0][0][0][0];
    #pragma unroll
    for (int k2 = 0; k2 < 2; ++k2) {
      #pragma unroll
      for (int r = 0; r < 4; ++r) {
        const int row = q * 4 + r;          // row = 2*t_local + batch
        f32x4 v;
        v[0] = accf[0][k2][r] + bL[0][k2];
        v[1] = accf[1][k2][r] + bL[1][k2];
        v[2] = accf[2][k2][r] + bL[2][k2];
        v[3] = accf[3][k2][r] + bL[3][k2];
        *(f32x4*)(dst + (size_t)(row * 64 + (kbase + k2) * 16 + col) * 4) = v;
      }
    }
  };

  // ---- w4/w5: xg2[sg] = b2 + fs*(W_ih2 @ h1) from ring (k-half) ----
  auto produce_xg2 = [&](int sg) {
    const i32x4 a = *(const i32x4*)((const signed char*)h1ring +
                    (size_t)((((sg * SEG + tl) & 31) * 128) + axb * 64 + q * 16));
    i32x4 acc[4][2];
    #pragma unroll
    for (int g = 0; g < 4; ++g)
      #pragma unroll
      for (int k2 = 0; k2 < 2; ++k2)
        acc[g][k2] = __builtin_amdgcn_mfma_i32_16x16x64_i8(a, wq2[g][k2], zi, 0, 0, 0);
    float* dst = &xg2b[sg & 1][0][0][0][0];
    #pragma unroll
    for (int k2 = 0; k2 < 2; ++k2) {
      #pragma unroll
      for (int r = 0; r < 4; ++r) {
        const int row = q * 4 + r;
        f32x4 v;
        v[0] = bL[0][k2] + fsx[0][k2] * (float)acc[0][k2][r];
        v[1] = bL[1][k2] + fsx[1][k2] * (float)acc[1][k2][r];
        v[2] = bL[2][k2] + fsx[2][k2] * (float)acc[2][k2][r];
        v[3] = bL[3][k2] + fsx[3][k2] * (float)acc[3][k2][r];
        *(f32x4*)(dst + (size_t)(row * 64 + (kbase + k2) * 16 + col) * 4) = v;
      }
    }
  };

  // ---- recurrence: 8 steps, one batch, one unit per lane, barrier-free ----
  auto run_seg = [&](const float* XG, signed char* RING, int RM, int t0, int isl2) {
    __builtin_amdgcn_s_setprio(1);
    #pragma unroll
    for (int j8 = 0; j8 < SEG; ++j8) {
      const int tt = t0 + j8;
      // previous h, replicated M: all lanes in a q-group read the same 16B
      const i32x4 a = *(const i32x4*)(RING + ((tt - 1) & RM) * 128 + myb * 64 + q * 16);
      // this lane's 4 gate pre-acts from producer (contiguous 16B/lane)
      const f32x4 xv = *(const f32x4*)(XG + (size_t)((j8 * 2 + myb) * 64 + l) * 4);
      i32x4 acc[4][4];
      #pragma unroll
      for (int g = 0; g < 4; ++g)
        #pragma unroll
        for (int k = 0; k < 4; ++k)
          acc[g][k] = __builtin_amdgcn_mfma_i32_16x16x64_i8(a, wq[g][k], zi, 0, 0, 0);
      // lane's unit u = l lives in tile k = q (static-index cndmask tree)
      float p[4];
      #pragma unroll
      for (int g = 0; g < 4; ++g) {
        const int v01 = (q & 1) ? acc[g][1][0] : acc[g][0][0];
        const int v23 = (q & 1) ? acc[g][3][0] : acc[g][2][0];
        const int ai  = (q & 2) ? v23 : v01;
        p[g] = xv[g] + fsa[g] * (float)ai;
      }
      const float gi = sigm2(p[0]), gf = sigm2(p[1]);
      const float gg = tanhg2(p[2]), go = sigm2(p[3]);
      c = gf * c + gi * gg;
      const float hv = go * tanhc(c);
      RING[(tt & RM) * 128 + myb * 64 + l] = (signed char)__float2int_rn(hv * 127.0f);
      if (isl2 && tt == T_STEPS - 1) hfin[myb][l] = hv;
    }
    __builtin_amdgcn_s_setprio(0);
  };

  // ---- prime xg1 for segment 0 (ring zero-writes also drain here) ----
  if (w >= 6) produce_xg1(0);
  barrier_lds();

  // ---- segmented pipeline ----
  for (int s = 0; s <= NSEG + 1; ++s) {
    if (w < 2) {
      if (s < NSEG)
        run_seg(&xg1b[s & 1][0][0][0][0], (signed char*)h1ring, 31, s * SEG, 0);
    } else if (w < 4) {
      const int sg = s - 2;
      if (sg >= 0)
        run_seg(&xg2b[sg & 1][0][0][0][0], (signed char*)h2ring, 1, sg * SEG, 1);
    } else if (w < 6) {
      const int sg = s - 1;
      if (sg >= 0 && sg < NSEG) produce_xg2(sg);
    } else {
      if (s + 1 < NSEG) produce_xg1(s + 1);
    }
    barrier_lds();
  }

  __syncthreads();   // full drain before epilogue

  // ---- head: y = LN(relu(hT@fc1^T+b1)@fc2^T+b2), 2 batch rows ----
  if (t < 256) {
    const int bi = t >> 7, j = t & 127;
    float accv = fc1_b[j];
    const float4* w4 = (const float4*)(fc1_w + j * 64);
    const float4* h4 = (const float4*)hfin[bi];
    #pragma unroll
    for (int qq = 0; qq < 16; ++qq) {
      float4 wv = w4[qq]; float4 hv = h4[qq];
      accv += wv.x * hv.x + wv.y * hv.y + wv.z * hv.z + wv.w * hv.w;
    }
    y1s[bi][j] = fmaxf(accv, 0.0f);
  }
  __syncthreads();
  if (t < 256) {
    const int bi = t >> 7, j = t & 127;
    float accv = fc2_b[j];
    const float4* w4 = (const float4*)(fc2_w + j * 128);
    const float4* y4 = (const float4*)y1s[bi];
    #pragma unroll
    for (int qq = 0; qq < 32; ++qq) {
      float4 wv = w4[qq]; float4 yv = y4[qq];
      accv += wv.x * yv.x + wv.y * yv.y + wv.z * yv.z + wv.w * yv.w;
    }
    y2s[bi][j] = accv;
  }
  __syncthreads();
  if (t < 128) {
    const int bi = t >> 6, jj = t & 63;
    float s  = y2s[bi][jj] + y2s[bi][64 + jj];
    float qs = y2s[bi][jj] * y2s[bi][jj] + y2s[bi][64 + jj] * y2s[bi][64 + jj];
    #pragma unroll
    for (int off = 32; off > 0; off >>= 1) {
      s  += __shfl_down(s, off, 64);
      qs += __shfl_down(qs, off, 64);
    }
    if (jj == 0) {
      const float mu  = s * (1.0f / 128.0f);
      const float var = qs * (1.0f / 128.0f) - mu * mu;
      redmu[bi] = mu;
      redrs[bi] = rsqrtf(var + 1e-5f);
    }
  }
  __syncthreads();
  if (t < 256) {
    const int bi = t >> 7, j = t & 127;
    out[(size_t)(2 * blk + bi) * 128 + j] =
        (y2s[bi][j] - redmu[bi]) * redrs[bi] * ln_g[j] + ln_b[j];
  }
}

extern "C" void kernel_launch(void* const* d_in, const int* in_sizes, int n_in,
                              void* d_out, int out_size, void* d_ws, size_t ws_size,
                              hipStream_t stream) {
  const float* x     = (const float*)d_in[0];
  const float* w_ih1 = (const float*)d_in[1];
  const float* w_hh1 = (const float*)d_in[2];
  const float* b_ih1 = (const float*)d_in[3];
  const float* b_hh1 = (const float*)d_in[4];
  const float* w_ih2 = (const float*)d_in[5];
  const float* w_hh2 = (const float*)d_in[6];
  const float* b_ih2 = (const float*)d_in[7];
  const float* b_hh2 = (const float*)d_in[8];
  const float* fc1_w = (const float*)d_in[9];
  const float* fc1_b = (const float*)d_in[10];
  const float* fc2_w = (const float*)d_in[11];
  const float* fc2_b = (const float*)d_in[12];
  const float* ln_g  = (const float*)d_in[13];
  const float* ln_b  = (const float*)d_in[14];
  float* out = (float*)d_out;

  lstm_fused<<<NBLK, 512, 0, stream>>>(x, w_ih1, w_hh1, b_ih1, b_hh1,
                                       w_ih2, w_hh2, b_ih2, b_hh2,
                                       fc1_w, fc1_b, fc2_w, fc2_b,
                                       ln_g, ln_b, out);
}